// Round 12
// baseline (146.682 us; speedup 1.0000x reference)
//
#include <hip/hip_runtime.h>
#include <hip/hip_bf16.h>

#define BATCH 2
#define SEQ 2048
#define DMODEL 768
#define NHEADS 12
#define NKV 4
#define DHEAD 64
#define WIN 512
#define GLB 64
#define ROWS (BATCH * SEQ)  // 4096

typedef short short8 __attribute__((ext_vector_type(8)));
typedef float f32x4 __attribute__((ext_vector_type(4)));

// fp32 -> bf16 bits, round-to-nearest-even (finite inputs only)
__device__ inline short f2bs(float f) {
    unsigned u = __float_as_uint(f);
    return (short)((u + 0x7fffu + ((u >> 16) & 1u)) >> 16);
}

// async global->LDS DMA, 16B/lane: LDS dest = wave-uniform base + lane*16.
__device__ inline void cp16(const short* g, short* l) {
    __builtin_amdgcn_global_load_lds(
        (const __attribute__((address_space(1))) unsigned int*)g,
        (__attribute__((address_space(3))) unsigned int*)l, 16, 0, 0);
}

// ---------------------------------------------------------------------------
// Weight transposes (blocks 0..1535) + x fp32->bf16 convert (blocks 1536..3071).
// ---------------------------------------------------------------------------
__global__ __launch_bounds__(256) void transp_all(
    const float* __restrict__ wq, const float* __restrict__ wk,
    const float* __restrict__ wv, const float* __restrict__ wo,
    short* __restrict__ wqkvT, short* __restrict__ woT,
    const float* __restrict__ x, short* __restrict__ xb) {
    __shared__ float t[32][33];
    int bid = blockIdx.x;
    if (bid >= 1536) {
        const long i = ((long)(bid - 1536) * 256 + threadIdx.x) * 8;
        float ff[8];
        *(float4*)&ff[0] = ((const float4*)(x + i))[0];
        *(float4*)&ff[4] = ((const float4*)(x + i))[1];
        short8 o;
#pragma unroll
        for (int j = 0; j < 8; ++j) o[j] = f2bs(ff[j]);
        *(short8*)(xb + i) = o;
        return;
    }
    const float* src; short* dst; int N;
    if (bid < 576)      { src = wq; dst = wqkvT; N = DMODEL; }
    else if (bid < 768) { src = wk; dst = wqkvT + DMODEL * DMODEL; N = 256; bid -= 576; }
    else if (bid < 960) { src = wv; dst = wqkvT + (DMODEL + 256) * DMODEL; N = 256; bid -= 768; }
    else                { src = wo; dst = woT; N = DMODEL; bid -= 960; }
    const int ntx = N >> 5;
    const int k0 = (bid / ntx) << 5, n0 = (bid % ntx) << 5;
    const int x_ = threadIdx.x & 31, y = threadIdx.x >> 5;
#pragma unroll
    for (int i = 0; i < 32; i += 8)
        t[y + i][x_] = src[(long)(k0 + y + i) * N + n0 + x_];
    __syncthreads();
#pragma unroll
    for (int i = 0; i < 32; i += 8)
        dst[(long)(n0 + y + i) * DMODEL + k0 + x_] = f2bs(t[x_][y + i]);
}

// ---------------------------------------------------------------------------
// MFMA GEMM (TN), R6 structure verbatim: BM=64 x BN=128, 2 LDS buffers
// (48 KB -> 3 blocks/CU; TLP hides the vmcnt(0) drain), async global_load_lds
// staging with pre-swizzled source. MODE 1 epilogue fuses K-RoPE (fp32 cache
// + bf16 Kb) and V (fp32 cache + bf16 transposed panels Vt); Q written fp32.
// ---------------------------------------------------------------------------
template <int MODE>
__global__ __launch_bounds__(256) void gemm_tn(
    const short* __restrict__ A, const short* __restrict__ Bt,
    float* __restrict__ Cq, float* __restrict__ Ck, float* __restrict__ Cv,
    short* __restrict__ Kb, short* __restrict__ Vt, int M, int N, int K) {
    __shared__ short As_[2][64 * 64];
    __shared__ short Bs_[2][128 * 64];
    const int tid = threadIdx.x;
    const int lane = tid & 63, w = tid >> 6;
    const int m_ = lane & 15, quad = lane >> 4;
    const int sw = m_ & 7;
    const int wm = w >> 1, wn = w & 1;
    const long bm = (long)blockIdx.y * 64, bn = (long)blockIdx.x * 128;
    const int soff = (lane >> 3) * K + (((lane & 7) ^ (lane >> 3)) << 3);

    f32x4 acc[2][4];
#pragma unroll
    for (int i = 0; i < 2; ++i)
#pragma unroll
        for (int j = 0; j < 4; ++j) acc[i][j] = (f32x4){0.f, 0.f, 0.f, 0.f};

    auto stage = [&](int k0, int bs) {
#pragma unroll
        for (int r = 0; r < 6; ++r) {
            const int ch = w * 6 + r;
            if (ch < 8)
                cp16(A + (bm + (ch << 3)) * K + k0 + soff, &As_[bs][ch << 9]);
            else
                cp16(Bt + (bn + ((ch - 8) << 3)) * K + k0 + soff,
                     &Bs_[bs][(ch - 8) << 9]);
        }
    };

    stage(0, 0);
    asm volatile("s_waitcnt vmcnt(0)" ::: "memory");
    asm volatile("s_barrier" ::: "memory");

    const int nk = K >> 6;
    for (int ks = 0; ks < nk; ++ks) {
        const int bs = ks & 1;
        if (ks + 1 < nk) stage((ks + 1) << 6, bs ^ 1);
#pragma unroll
        for (int kh = 0; kh < 2; ++kh) {
            short8 af[2], bf[4];
#pragma unroll
            for (int i = 0; i < 2; ++i)
                af[i] = *(const short8*)&As_[bs][(wm * 32 + i * 16 + m_) * 64 + (((kh * 4 + quad) ^ sw) << 3)];
#pragma unroll
            for (int j = 0; j < 4; ++j)
                bf[j] = *(const short8*)&Bs_[bs][(wn * 64 + j * 16 + m_) * 64 + (((kh * 4 + quad) ^ sw) << 3)];
            __builtin_amdgcn_s_setprio(1);
#pragma unroll
            for (int i = 0; i < 2; ++i)
#pragma unroll
                for (int j = 0; j < 4; ++j)
                    acc[i][j] = __builtin_amdgcn_mfma_f32_16x16x32_bf16(af[i], bf[j], acc[i][j], 0, 0, 0);
            __builtin_amdgcn_s_setprio(0);
        }
        if (ks + 1 < nk) {
            asm volatile("s_waitcnt vmcnt(0)" ::: "memory");
            asm volatile("s_barrier" ::: "memory");
        }
    }

    if (MODE == 0 || bn < DMODEL) {
        const int stride = (MODE == 1) ? DMODEL : N;
#pragma unroll
        for (int i = 0; i < 2; ++i) {
            const int row0 = (int)bm + wm * 32 + i * 16 + quad * 4;
#pragma unroll
            for (int j = 0; j < 4; ++j) {
                const int col = (int)bn + wn * 64 + j * 16 + m_;
#pragma unroll
                for (int r = 0; r < 4; ++r)
                    Cq[(long)(row0 + r) * stride + col] = acc[i][j][r];
            }
        }
    } else if (bn < DMODEL + 256) {
        // K path: fused RoPE. d = j*16+m_ (j in {0,1}), partner at acc[i][j+2].
        const int kvh = ((int)(bn - DMODEL) >> 6) + wn;
#pragma unroll
        for (int i = 0; i < 2; ++i) {
            const int row0 = (int)bm + wm * 32 + i * 16 + quad * 4;
            const int t = row0 & (SEQ - 1), b = row0 >> 11;
            const long base0 = ((long)(b * NKV + kvh) * SEQ) << 6;
#pragma unroll
            for (int j = 0; j < 2; ++j) {
                const int d = j * 16 + m_;
                const float invf = expf(-(float)d * 0.2878231366f);
#pragma unroll
                for (int r = 0; r < 4; ++r) {
                    const int tt = t + r;
                    float s_, c_;
                    sincosf((float)tt * invf, &s_, &c_);
                    const float x1 = acc[i][j][r], x2 = acc[i][j + 2][r];
                    const float y1 = x1 * c_ - x2 * s_;
                    const float y2 = x2 * c_ + x1 * s_;
                    const long o = base0 + ((long)tt << 6) + d;
                    Ck[o] = y1;
                    Ck[o + 32] = y2;
                    Kb[o] = f2bs(y1);
                    Kb[o + 32] = f2bs(y2);
                }
            }
        }
    } else {
        // V path: fp32 cache + bf16 transposed panels Vt[bkv][t>>6][d][t&63]
        const int kvh = ((int)(bn - (DMODEL + 256)) >> 6) + wn;
#pragma unroll
        for (int i = 0; i < 2; ++i) {
            const int row0 = (int)bm + wm * 32 + i * 16 + quad * 4;
            const int t = row0 & (SEQ - 1), b = row0 >> 11;
            const long bkvi = (long)(b * NKV + kvh);
            const long vtbase = (bkvi << 17) + ((long)(t >> 6) << 12) + (t & 63);
#pragma unroll
            for (int j = 0; j < 4; ++j) {
                const int d = j * 16 + m_;
                union { short sh[4]; unsigned long long u; } pk;
#pragma unroll
                for (int r = 0; r < 4; ++r) {
                    const float v = acc[i][j][r];
                    Cv[((bkvi * SEQ + t + r) << 6) + d] = v;
                    pk.sh[r] = f2bs(v);
                }
                *(unsigned long long*)&Vt[vtbase + ((long)d << 6)] = pk.u;
            }
        }
    }
}

// ---------------------------------------------------------------------------
// Flash v14 = R6's v10 verbatim + ONLY the exp2 folding: Q-RoPE scale is
// 0.125*log2(e) so S is in the log2 domain; softmax uses exp2f directly
// (v_exp_f32 is base-2 -- deletes the implicit x*log2e v_mul per exp).
// No inline-asm cvt_pk (m240: it regresses), no ordering remap.
// ---------------------------------------------------------------------------
__global__ __launch_bounds__(384) void flash6(
    const float* __restrict__ Qf, const short* __restrict__ Kb,
    const short* __restrict__ Vt, short* __restrict__ ATT) {
    __shared__ short Kbuf[2][64 * 64];
    __shared__ short Vbuf[2][64 * 64];
    __shared__ short Pl[6][16 * 64];
    const int tid = threadIdx.x;
    const int w = tid >> 6, lane = tid & 63;
    const int m_ = lane & 15, quad = lane >> 4;
    const int sw = m_ & 7;
    const int bkv = blockIdx.x >> 6;
    const int t0 = (63 - (blockIdx.x & 63)) << 5;   // heavy blocks first
    const int b = bkv >> 2, kvh = bkv & 3;
    const int h = kvh * 3 + (w >> 1);
    const int qg = w & 1;
    const int trw = t0 + (qg << 4);
    const int tq = trw + m_;       // this lane's q-row
    const long kgb = ((long)bkv * SEQ) << 6;        // Kb base (shorts)
    const long vgb = (long)bkv * SEQ * DHEAD;       // Vt base (shorts)

    const int soff = ((lane >> 3) << 6) + (((lane & 7) ^ (lane >> 3)) << 3);

    // Q fp32 load + fused RoPE -> bf16 B-frags.
    // Scale = (1/8) * log2(e): softmax then uses exp2 directly.
    short8 qf0, qf1;
    {
        const float* qpf = Qf + (long)(b * SEQ + tq) * DMODEL + h * DHEAD + quad * 8;
        float xx[8], yy[8];
        *(float4*)&xx[0] = ((const float4*)qpf)[0];
        *(float4*)&xx[4] = ((const float4*)qpf)[1];
        *(float4*)&yy[0] = ((const float4*)(qpf + 32))[0];
        *(float4*)&yy[4] = ((const float4*)(qpf + 32))[1];
#pragma unroll
        for (int jj = 0; jj < 8; ++jj) {
            const int j = quad * 8 + jj;
            const float inv = expf(-(float)j * 0.2878231366f);
            float s_, c_;
            sincosf((float)tq * inv, &s_, &c_);
            qf0[jj] = f2bs((xx[jj] * c_ - yy[jj] * s_) * 0.1803368867f);
            qf1[jj] = f2bs((yy[jj] * c_ + xx[jj] * s_) * 0.1803368867f);
        }
    }

    f32x4 of[4];
#pragma unroll
    for (int i = 0; i < 4; ++i) of[i] = (f32x4){0.f, 0.f, 0.f, 0.f};
    float mr = -1e30f, lr = 0.f;

    int wlo = t0 - (WIN - 1);      // FIRST row's window floor
    if (wlo < GLB) wlo = GLB;
    wlo &= ~63;
    const int nwin = (t0 + 31 >= wlo) ? (((t0 + 31 - wlo) >> 6) + 1) : 0;
    const int ntile = 1 + nwin;
    auto kb_of = [&](int j) { return (j == 0) ? 0 : (wlo + ((j - 1) << 6)); };

    auto stage = [&](int kb, int bs) {
#pragma unroll
        for (int r = 0; r < 3; ++r) {
            const int ch = w + 6 * r;
            if (ch < 8) {
                cp16(Kb + kgb + ((long)(kb + (ch << 3)) << 6) + soff,
                     &Kbuf[bs][ch << 9]);
            } else if (ch < 16) {
                const int cv = ch - 8;
                cp16(Vt + vgb + (((long)kb >> 6) << 12) + (cv << 9) + soff,
                     &Vbuf[bs][cv << 9]);
            }
        }
    };

    stage(kb_of(0), 0);
    asm volatile("s_waitcnt vmcnt(0)" ::: "memory");
    asm volatile("s_barrier" ::: "memory");

    for (int tI = 0; tI < ntile; ++tI) {
        const int kb = kb_of(tI);
        const int bs = tI & 1;
        if (tI + 1 < ntile) stage(kb_of(tI + 1), bs ^ 1);

        short8 kf[8], vf[8];
#pragma unroll
        for (int st = 0; st < 4; ++st)
#pragma unroll
            for (int hh = 0; hh < 2; ++hh)
                kf[st * 2 + hh] = *(const short8*)&Kbuf[bs][(st * 16 + m_) * 64 + (((hh * 4 + quad) ^ sw) << 3)];
#pragma unroll
        for (int dt = 0; dt < 4; ++dt)
#pragma unroll
            for (int kh = 0; kh < 2; ++kh)
                vf[dt * 2 + kh] = *(const short8*)&Vbuf[bs][(dt * 16 + m_) * 64 + (((kh * 4 + quad) ^ sw) << 3)];

        // S^T = K Q^T   (S already in log2 domain via Q scale)
        f32x4 s[4];
        __builtin_amdgcn_s_setprio(1);
#pragma unroll
        for (int st = 0; st < 4; ++st) {
            f32x4 a = (f32x4){0.f, 0.f, 0.f, 0.f};
            a = __builtin_amdgcn_mfma_f32_16x16x32_bf16(kf[st * 2 + 0], qf0, a, 0, 0, 0);
            a = __builtin_amdgcn_mfma_f32_16x16x32_bf16(kf[st * 2 + 1], qf1, a, 0, 0, 0);
            s[st] = a;
        }
        __builtin_amdgcn_s_setprio(0);

        const bool fully = (kb + 63 <= trw) &&
                           ((kb >= trw + 16 - WIN) || (kb + 63 < GLB) || (trw + 15 < GLB));
        if (!fully) {
#pragma unroll
            for (int st = 0; st < 4; ++st) {
#pragma unroll
                for (int r = 0; r < 4; ++r) {
                    const int key = kb + st * 16 + quad * 4 + r;
                    const bool ok = (key <= tq) && ((key > tq - WIN) || (key < GLB) || (tq < GLB));
                    if (!ok) s[st][r] = -1e30f;
                }
            }
        }

        float tm = -1e30f;
#pragma unroll
        for (int st = 0; st < 4; ++st)
#pragma unroll
            for (int r = 0; r < 4; ++r) tm = fmaxf(tm, s[st][r]);
        tm = fmaxf(tm, __shfl_xor(tm, 16, 64));
        tm = fmaxf(tm, __shfl_xor(tm, 32, 64));
        if (!__all(tm <= mr)) {
            const float mnew = fmaxf(mr, tm);
            const float alpha = exp2f(mr - mnew);
            mr = mnew;
            lr *= alpha;
#pragma unroll
            for (int dt = 0; dt < 4; ++dt)
#pragma unroll
                for (int r = 0; r < 4; ++r) of[dt][r] *= alpha;
        }
        float rs = 0.f;
#pragma unroll
        for (int st = 0; st < 4; ++st) {
            float p0 = exp2f(s[st][0] - mr);
            float p1 = exp2f(s[st][1] - mr);
            float p2 = exp2f(s[st][2] - mr);
            float p3 = exp2f(s[st][3] - mr);
            rs += (p0 + p1) + (p2 + p3);
            union { short sh[4]; unsigned long long u; } pk;
            pk.sh[0] = f2bs(p0); pk.sh[1] = f2bs(p1);
            pk.sh[2] = f2bs(p2); pk.sh[3] = f2bs(p3);
            *(unsigned long long*)&Pl[w][m_ * 64 + (((st * 2 + (quad >> 1)) ^ sw) << 3) + ((quad & 1) << 2)] = pk.u;
        }
        rs += __shfl_xor(rs, 16, 64);
        rs += __shfl_xor(rs, 32, 64);
        lr += rs;

        short8 pf[2];
#pragma unroll
        for (int kh = 0; kh < 2; ++kh)
            pf[kh] = *(const short8*)&Pl[w][m_ * 64 + (((kh * 4 + quad) ^ sw) << 3)];

        __builtin_amdgcn_s_setprio(1);
#pragma unroll
        for (int dt = 0; dt < 4; ++dt) {
            of[dt] = __builtin_amdgcn_mfma_f32_16x16x32_bf16(vf[dt * 2 + 0], pf[0], of[dt], 0, 0, 0);
            of[dt] = __builtin_amdgcn_mfma_f32_16x16x32_bf16(vf[dt * 2 + 1], pf[1], of[dt], 0, 0, 0);
        }
        __builtin_amdgcn_s_setprio(0);

        if (tI + 1 < ntile) {
            asm volatile("s_waitcnt vmcnt(0)" ::: "memory");
            asm volatile("s_barrier" ::: "memory");
        }
    }

    const float inv = 1.0f / lr;
    short* op = ATT + (long)(b * SEQ + tq) * DMODEL + h * DHEAD + quad * 4;
#pragma unroll
    for (int dt = 0; dt < 4; ++dt) {
        union { short sh[4]; unsigned long long u; } pk;
#pragma unroll
        for (int r = 0; r < 4; ++r) pk.sh[r] = f2bs(of[dt][r] * inv);
        *(unsigned long long*)(op + dt * 16) = pk.u;
    }
}

// ---------------------------------------------------------------------------
extern "C" void kernel_launch(void* const* d_in, const int* in_sizes, int n_in,
                              void* d_out, int out_size, void* d_ws, size_t ws_size,
                              hipStream_t stream) {
    const float* x = (const float*)d_in[0];
    const float* wq = (const float*)d_in[1];
    const float* wk = (const float*)d_in[2];
    const float* wv = (const float*)d_in[3];
    const float* wo = (const float*)d_in[4];
    float* out = (float*)d_out;
    float* out_k = out + (long)ROWS * DMODEL;
    float* out_v = out_k + (long)BATCH * NKV * SEQ * DHEAD;

    // ws (shorts): regA: wqkvT -> ATTb (sequential lifetimes) | woT | KbB | VtB | xb
    short* regA = (short*)d_ws;
    short* wqkvT = regA;
    short* ATTb = regA;
    short* woT = regA + (long)ROWS * DMODEL;
    short* KbB = woT + (long)DMODEL * DMODEL;
    short* VtB = KbB + (long)BATCH * NKV * SEQ * DHEAD;
    short* xb = VtB + (long)BATCH * NKV * SEQ * DHEAD;

    transp_all<<<3072, 256, 0, stream>>>(wq, wk, wv, wo, wqkvT, woT, x, xb);
    gemm_tn<1><<<dim3((DMODEL + 2 * NKV * DHEAD) / 128, ROWS / 64), 256, 0, stream>>>(
        xb, wqkvT, out, out_k, out_v, KbB, VtB, ROWS, DMODEL + 2 * NKV * DHEAD, DMODEL);
    flash6<<<BATCH * NKV * (SEQ / 32), 384, 0, stream>>>(out, KbB, VtB, ATTb);
    gemm_tn<0><<<dim3(DMODEL / 128, ROWS / 64), 256, 0, stream>>>(
        ATTb, woT, out, nullptr, nullptr, nullptr, nullptr, ROWS, DMODEL, DMODEL);
}

// Round 13
// 134.157 us; speedup vs baseline: 1.0934x; 1.0934x over previous
//
#include <hip/hip_runtime.h>
#include <hip/hip_bf16.h>

#define BATCH 2
#define SEQ 2048
#define DMODEL 768
#define NHEADS 12
#define NKV 4
#define DHEAD 64
#define WIN 512
#define GLB 64
#define ROWS (BATCH * SEQ)  // 4096

typedef short short8 __attribute__((ext_vector_type(8)));
typedef float f32x4 __attribute__((ext_vector_type(4)));

// fp32 -> bf16 bits, round-to-nearest-even (finite inputs only)
__device__ inline short f2bs(float f) {
    unsigned u = __float_as_uint(f);
    return (short)((u + 0x7fffu + ((u >> 16) & 1u)) >> 16);
}

// async global->LDS DMA, 16B/lane: LDS dest = wave-uniform base + lane*16.
__device__ inline void cp16(const short* g, short* l) {
    __builtin_amdgcn_global_load_lds(
        (const __attribute__((address_space(1))) unsigned int*)g,
        (__attribute__((address_space(3))) unsigned int*)l, 16, 0, 0);
}

// ---------------------------------------------------------------------------
// Weight transposes (blocks 0..1535) + x fp32->bf16 convert (blocks 1536..3071).
// ---------------------------------------------------------------------------
__global__ __launch_bounds__(256) void transp_all(
    const float* __restrict__ wq, const float* __restrict__ wk,
    const float* __restrict__ wv, const float* __restrict__ wo,
    short* __restrict__ wqkvT, short* __restrict__ woT,
    const float* __restrict__ x, short* __restrict__ xb) {
    __shared__ float t[32][33];
    int bid = blockIdx.x;
    if (bid >= 1536) {
        const long i = ((long)(bid - 1536) * 256 + threadIdx.x) * 8;
        float ff[8];
        *(float4*)&ff[0] = ((const float4*)(x + i))[0];
        *(float4*)&ff[4] = ((const float4*)(x + i))[1];
        short8 o;
#pragma unroll
        for (int j = 0; j < 8; ++j) o[j] = f2bs(ff[j]);
        *(short8*)(xb + i) = o;
        return;
    }
    const float* src; short* dst; int N;
    if (bid < 576)      { src = wq; dst = wqkvT; N = DMODEL; }
    else if (bid < 768) { src = wk; dst = wqkvT + DMODEL * DMODEL; N = 256; bid -= 576; }
    else if (bid < 960) { src = wv; dst = wqkvT + (DMODEL + 256) * DMODEL; N = 256; bid -= 768; }
    else                { src = wo; dst = woT; N = DMODEL; bid -= 960; }
    const int ntx = N >> 5;
    const int k0 = (bid / ntx) << 5, n0 = (bid % ntx) << 5;
    const int x_ = threadIdx.x & 31, y = threadIdx.x >> 5;
#pragma unroll
    for (int i = 0; i < 32; i += 8)
        t[y + i][x_] = src[(long)(k0 + y + i) * N + n0 + x_];
    __syncthreads();
#pragma unroll
    for (int i = 0; i < 32; i += 8)
        dst[(long)(n0 + y + i) * DMODEL + k0 + x_] = f2bs(t[x_][y + i]);
}

// ---------------------------------------------------------------------------
// MFMA GEMM (TN), v3: BM=64 x BN=128 tiles (gemm1 grid 640, gemm2 384 -- TLP
// hides the per-K-step vmcnt(0) drain; 48 KB LDS -> 3 blocks/CU). Staging via
// async global_load_lds with pre-swizzled source (flash6-proven). MODE 1
// epilogue FUSES prep_kv: K-RoPE in-register (pairs (d,d+32) = acc[i][j] /
// acc[i][j+2] in the same lane; identical expf/sincosf/f2bs arithmetic on
// identical fp32 values) writing roped fp32 cache + bf16 Kb; V written as
// fp32 cache + bf16 transposed panels Vt. prep_kv kernel deleted.
// ---------------------------------------------------------------------------
template <int MODE>
__global__ __launch_bounds__(256) void gemm_tn(
    const short* __restrict__ A, const short* __restrict__ Bt,
    float* __restrict__ Cq, float* __restrict__ Ck, float* __restrict__ Cv,
    short* __restrict__ Kb, short* __restrict__ Vt, int M, int N, int K) {
    __shared__ short As_[2][64 * 64];
    __shared__ short Bs_[2][128 * 64];
    const int tid = threadIdx.x;
    const int lane = tid & 63, w = tid >> 6;
    const int m_ = lane & 15, quad = lane >> 4;
    const int sw = m_ & 7;
    const int wm = w >> 1, wn = w & 1;
    const long bm = (long)blockIdx.y * 64, bn = (long)blockIdx.x * 128;
    // per-lane inverse-swizzled source offset (linear LDS dest)
    const int soff = (lane >> 3) * K + (((lane & 7) ^ (lane >> 3)) << 3);

    f32x4 acc[2][4];
#pragma unroll
    for (int i = 0; i < 2; ++i)
#pragma unroll
        for (int j = 0; j < 4; ++j) acc[i][j] = (f32x4){0.f, 0.f, 0.f, 0.f};

    // 24 chunks of 1KB per K-step (A 8 | B 16); wave w takes 6.
    auto stage = [&](int k0, int bs) {
#pragma unroll
        for (int r = 0; r < 6; ++r) {
            const int ch = w * 6 + r;
            if (ch < 8)
                cp16(A + (bm + (ch << 3)) * K + k0 + soff, &As_[bs][ch << 9]);
            else
                cp16(Bt + (bn + ((ch - 8) << 3)) * K + k0 + soff,
                     &Bs_[bs][(ch - 8) << 9]);
        }
    };

    stage(0, 0);
    asm volatile("s_waitcnt vmcnt(0)" ::: "memory");
    asm volatile("s_barrier" ::: "memory");

    const int nk = K >> 6;
    for (int ks = 0; ks < nk; ++ks) {
        const int bs = ks & 1;
        if (ks + 1 < nk) stage((ks + 1) << 6, bs ^ 1);
#pragma unroll
        for (int kh = 0; kh < 2; ++kh) {
            short8 af[2], bf[4];
#pragma unroll
            for (int i = 0; i < 2; ++i)
                af[i] = *(const short8*)&As_[bs][(wm * 32 + i * 16 + m_) * 64 + (((kh * 4 + quad) ^ sw) << 3)];
#pragma unroll
            for (int j = 0; j < 4; ++j)
                bf[j] = *(const short8*)&Bs_[bs][(wn * 64 + j * 16 + m_) * 64 + (((kh * 4 + quad) ^ sw) << 3)];
            __builtin_amdgcn_s_setprio(1);
#pragma unroll
            for (int i = 0; i < 2; ++i)
#pragma unroll
                for (int j = 0; j < 4; ++j)
                    acc[i][j] = __builtin_amdgcn_mfma_f32_16x16x32_bf16(af[i], bf[j], acc[i][j], 0, 0, 0);
            __builtin_amdgcn_s_setprio(0);
        }
        if (ks + 1 < nk) {
            asm volatile("s_waitcnt vmcnt(0)" ::: "memory");
            asm volatile("s_barrier" ::: "memory");
        }
    }

    if (MODE == 0 || bn < DMODEL) {
        // plain fp32 store (Q region for MODE 1; whole C for MODE 0)
        const int stride = (MODE == 1) ? DMODEL : N;
#pragma unroll
        for (int i = 0; i < 2; ++i) {
            const int row0 = (int)bm + wm * 32 + i * 16 + quad * 4;
#pragma unroll
            for (int j = 0; j < 4; ++j) {
                const int col = (int)bn + wn * 64 + j * 16 + m_;
#pragma unroll
                for (int r = 0; r < 4; ++r)
                    Cq[(long)(row0 + r) * stride + col] = acc[i][j][r];
            }
        }
    } else if (bn < DMODEL + 256) {
        // K path: fused RoPE. d = j*16+m_ (j in {0,1}), partner at acc[i][j+2].
        const int kvh = ((int)(bn - DMODEL) >> 6) + wn;
#pragma unroll
        for (int i = 0; i < 2; ++i) {
            const int row0 = (int)bm + wm * 32 + i * 16 + quad * 4;
            const int t = row0 & (SEQ - 1), b = row0 >> 11;
            const long base0 = ((long)(b * NKV + kvh) * SEQ) << 6;
#pragma unroll
            for (int j = 0; j < 2; ++j) {
                const int d = j * 16 + m_;
                const float invf = expf(-(float)d * 0.2878231366f);
#pragma unroll
                for (int r = 0; r < 4; ++r) {
                    const int tt = t + r;
                    float s_, c_;
                    sincosf((float)tt * invf, &s_, &c_);
                    const float x1 = acc[i][j][r], x2 = acc[i][j + 2][r];
                    const float y1 = x1 * c_ - x2 * s_;
                    const float y2 = x2 * c_ + x1 * s_;
                    const long o = base0 + ((long)tt << 6) + d;
                    Ck[o] = y1;
                    Ck[o + 32] = y2;
                    Kb[o] = f2bs(y1);
                    Kb[o + 32] = f2bs(y2);
                }
            }
        }
    } else {
        // V path: fp32 cache + bf16 transposed panels Vt[bkv][t>>6][d][t&63]
        const int kvh = ((int)(bn - (DMODEL + 256)) >> 6) + wn;
#pragma unroll
        for (int i = 0; i < 2; ++i) {
            const int row0 = (int)bm + wm * 32 + i * 16 + quad * 4;
            const int t = row0 & (SEQ - 1), b = row0 >> 11;
            const long bkvi = (long)(b * NKV + kvh);
            const long vtbase = (bkvi << 17) + ((long)(t >> 6) << 12) + (t & 63);
#pragma unroll
            for (int j = 0; j < 4; ++j) {
                const int d = j * 16 + m_;
                union { short sh[4]; unsigned long long u; } pk;
#pragma unroll
                for (int r = 0; r < 4; ++r) {
                    const float v = acc[i][j][r];
                    Cv[((bkvi * SEQ + t + r) << 6) + d] = v;
                    pk.sh[r] = f2bs(v);
                }
                *(unsigned long long*)&Vt[vtbase + ((long)d << 6)] = pk.u;
            }
        }
    }
}

// ---------------------------------------------------------------------------
// Flash v10 (R6 verbatim): fused Q-RoPE prologue; async global_load_lds
// staging with pre-swizzled source; 1-tile prefetch; vmcnt(0)+raw s_barrier.
// ---------------------------------------------------------------------------
__global__ __launch_bounds__(384) void flash6(
    const float* __restrict__ Qf, const short* __restrict__ Kb,
    const short* __restrict__ Vt, short* __restrict__ ATT) {
    __shared__ short Kbuf[2][64 * 64];
    __shared__ short Vbuf[2][64 * 64];
    __shared__ short Pl[6][16 * 64];
    const int tid = threadIdx.x;
    const int w = tid >> 6, lane = tid & 63;
    const int m_ = lane & 15, quad = lane >> 4;
    const int sw = m_ & 7;
    const int bkv = blockIdx.x >> 6;
    const int t0 = (63 - (blockIdx.x & 63)) << 5;   // heavy blocks first
    const int b = bkv >> 2, kvh = bkv & 3;
    const int h = kvh * 3 + (w >> 1);
    const int qg = w & 1;
    const int trw = t0 + (qg << 4);
    const int tq = trw + m_;       // this lane's q-row
    const long kgb = ((long)bkv * SEQ) << 6;        // Kb base (shorts)
    const long vgb = (long)bkv * SEQ * DHEAD;       // Vt base (shorts)

    const int soff = ((lane >> 3) << 6) + (((lane & 7) ^ (lane >> 3)) << 3);

    // Q fp32 load + fused RoPE -> bf16 B-frags (scale 1/8 folded)
    short8 qf0, qf1;
    {
        const float* qpf = Qf + (long)(b * SEQ + tq) * DMODEL + h * DHEAD + quad * 8;
        float xx[8], yy[8];
        *(float4*)&xx[0] = ((const float4*)qpf)[0];
        *(float4*)&xx[4] = ((const float4*)qpf)[1];
        *(float4*)&yy[0] = ((const float4*)(qpf + 32))[0];
        *(float4*)&yy[4] = ((const float4*)(qpf + 32))[1];
#pragma unroll
        for (int jj = 0; jj < 8; ++jj) {
            const int j = quad * 8 + jj;
            const float inv = expf(-(float)j * 0.2878231366f);
            float s_, c_;
            sincosf((float)tq * inv, &s_, &c_);
            qf0[jj] = f2bs((xx[jj] * c_ - yy[jj] * s_) * 0.125f);
            qf1[jj] = f2bs((yy[jj] * c_ + xx[jj] * s_) * 0.125f);
        }
    }

    f32x4 of[4];
#pragma unroll
    for (int i = 0; i < 4; ++i) of[i] = (f32x4){0.f, 0.f, 0.f, 0.f};
    float mr = -1e30f, lr = 0.f;

    int wlo = t0 - (WIN - 1);      // FIRST row's window floor
    if (wlo < GLB) wlo = GLB;
    wlo &= ~63;
    const int nwin = (t0 + 31 >= wlo) ? (((t0 + 31 - wlo) >> 6) + 1) : 0;
    const int ntile = 1 + nwin;
    auto kb_of = [&](int j) { return (j == 0) ? 0 : (wlo + ((j - 1) << 6)); };

    auto stage = [&](int kb, int bs) {
#pragma unroll
        for (int r = 0; r < 3; ++r) {
            const int ch = w + 6 * r;
            if (ch < 8) {
                cp16(Kb + kgb + ((long)(kb + (ch << 3)) << 6) + soff,
                     &Kbuf[bs][ch << 9]);
            } else if (ch < 16) {
                const int cv = ch - 8;
                cp16(Vt + vgb + (((long)kb >> 6) << 12) + (cv << 9) + soff,
                     &Vbuf[bs][cv << 9]);
            }
        }
    };

    stage(kb_of(0), 0);
    asm volatile("s_waitcnt vmcnt(0)" ::: "memory");
    asm volatile("s_barrier" ::: "memory");

    for (int tI = 0; tI < ntile; ++tI) {
        const int kb = kb_of(tI);
        const int bs = tI & 1;
        if (tI + 1 < ntile) stage(kb_of(tI + 1), bs ^ 1);

        short8 kf[8], vf[8];
#pragma unroll
        for (int st = 0; st < 4; ++st)
#pragma unroll
            for (int hh = 0; hh < 2; ++hh)
                kf[st * 2 + hh] = *(const short8*)&Kbuf[bs][(st * 16 + m_) * 64 + (((hh * 4 + quad) ^ sw) << 3)];
#pragma unroll
        for (int dt = 0; dt < 4; ++dt)
#pragma unroll
            for (int kh = 0; kh < 2; ++kh)
                vf[dt * 2 + kh] = *(const short8*)&Vbuf[bs][(dt * 16 + m_) * 64 + (((kh * 4 + quad) ^ sw) << 3)];

        // S^T = K Q^T
        f32x4 s[4];
        __builtin_amdgcn_s_setprio(1);
#pragma unroll
        for (int st = 0; st < 4; ++st) {
            f32x4 a = (f32x4){0.f, 0.f, 0.f, 0.f};
            a = __builtin_amdgcn_mfma_f32_16x16x32_bf16(kf[st * 2 + 0], qf0, a, 0, 0, 0);
            a = __builtin_amdgcn_mfma_f32_16x16x32_bf16(kf[st * 2 + 1], qf1, a, 0, 0, 0);
            s[st] = a;
        }
        __builtin_amdgcn_s_setprio(0);

        const bool fully = (kb + 63 <= trw) &&
                           ((kb >= trw + 16 - WIN) || (kb + 63 < GLB) || (trw + 15 < GLB));
        if (!fully) {
#pragma unroll
            for (int st = 0; st < 4; ++st) {
#pragma unroll
                for (int r = 0; r < 4; ++r) {
                    const int key = kb + st * 16 + quad * 4 + r;
                    const bool ok = (key <= tq) && ((key > tq - WIN) || (key < GLB) || (tq < GLB));
                    if (!ok) s[st][r] = -1e30f;
                }
            }
        }

        float tm = -1e30f;
#pragma unroll
        for (int st = 0; st < 4; ++st)
#pragma unroll
            for (int r = 0; r < 4; ++r) tm = fmaxf(tm, s[st][r]);
        tm = fmaxf(tm, __shfl_xor(tm, 16, 64));
        tm = fmaxf(tm, __shfl_xor(tm, 32, 64));
        if (!__all(tm <= mr)) {
            const float mnew = fmaxf(mr, tm);
            const float alpha = __expf(mr - mnew);
            mr = mnew;
            lr *= alpha;
#pragma unroll
            for (int dt = 0; dt < 4; ++dt)
#pragma unroll
                for (int r = 0; r < 4; ++r) of[dt][r] *= alpha;
        }
        float rs = 0.f;
#pragma unroll
        for (int st = 0; st < 4; ++st) {
            float p0 = __expf(s[st][0] - mr);
            float p1 = __expf(s[st][1] - mr);
            float p2 = __expf(s[st][2] - mr);
            float p3 = __expf(s[st][3] - mr);
            rs += (p0 + p1) + (p2 + p3);
            union { short sh[4]; unsigned long long u; } pk;
            pk.sh[0] = f2bs(p0); pk.sh[1] = f2bs(p1);
            pk.sh[2] = f2bs(p2); pk.sh[3] = f2bs(p3);
            *(unsigned long long*)&Pl[w][m_ * 64 + (((st * 2 + (quad >> 1)) ^ sw) << 3) + ((quad & 1) << 2)] = pk.u;
        }
        rs += __shfl_xor(rs, 16, 64);
        rs += __shfl_xor(rs, 32, 64);
        lr += rs;

        short8 pf[2];
#pragma unroll
        for (int kh = 0; kh < 2; ++kh)
            pf[kh] = *(const short8*)&Pl[w][m_ * 64 + (((kh * 4 + quad) ^ sw) << 3)];

        __builtin_amdgcn_s_setprio(1);
#pragma unroll
        for (int dt = 0; dt < 4; ++dt) {
            of[dt] = __builtin_amdgcn_mfma_f32_16x16x32_bf16(vf[dt * 2 + 0], pf[0], of[dt], 0, 0, 0);
            of[dt] = __builtin_amdgcn_mfma_f32_16x16x32_bf16(vf[dt * 2 + 1], pf[1], of[dt], 0, 0, 0);
        }
        __builtin_amdgcn_s_setprio(0);

        if (tI + 1 < ntile) {
            asm volatile("s_waitcnt vmcnt(0)" ::: "memory");
            asm volatile("s_barrier" ::: "memory");
        }
    }

    const float inv = 1.0f / lr;
    short* op = ATT + (long)(b * SEQ + tq) * DMODEL + h * DHEAD + quad * 4;
#pragma unroll
    for (int dt = 0; dt < 4; ++dt) {
        union { short sh[4]; unsigned long long u; } pk;
#pragma unroll
        for (int r = 0; r < 4; ++r) pk.sh[r] = f2bs(of[dt][r] * inv);
        *(unsigned long long*)(op + dt * 16) = pk.u;
    }
}

// ---------------------------------------------------------------------------
extern "C" void kernel_launch(void* const* d_in, const int* in_sizes, int n_in,
                              void* d_out, int out_size, void* d_ws, size_t ws_size,
                              hipStream_t stream) {
    const float* x = (const float*)d_in[0];
    const float* wq = (const float*)d_in[1];
    const float* wk = (const float*)d_in[2];
    const float* wv = (const float*)d_in[3];
    const float* wo = (const float*)d_in[4];
    float* out = (float*)d_out;
    float* out_k = out + (long)ROWS * DMODEL;
    float* out_v = out_k + (long)BATCH * NKV * SEQ * DHEAD;

    // ws (shorts): regA: wqkvT -> ATTb (sequential lifetimes) | woT | KbB | VtB | xb
    short* regA = (short*)d_ws;
    short* wqkvT = regA;
    short* ATTb = regA;
    short* woT = regA + (long)ROWS * DMODEL;
    short* KbB = woT + (long)DMODEL * DMODEL;
    short* VtB = KbB + (long)BATCH * NKV * SEQ * DHEAD;
    short* xb = VtB + (long)BATCH * NKV * SEQ * DHEAD;

    transp_all<<<3072, 256, 0, stream>>>(wq, wk, wv, wo, wqkvT, woT, x, xb);
    gemm_tn<1><<<dim3((DMODEL + 2 * NKV * DHEAD) / 128, ROWS / 64), 256, 0, stream>>>(
        xb, wqkvT, out, out_k, out_v, KbB, VtB, ROWS, DMODEL + 2 * NKV * DHEAD, DMODEL);
    flash6<<<BATCH * NKV * (SEQ / 32), 384, 0, stream>>>(out, KbB, VtB, ATTb);
    gemm_tn<0><<<dim3(DMODEL / 128, ROWS / 64), 256, 0, stream>>>(
        ATTb, woT, out, nullptr, nullptr, nullptr, nullptr, ROWS, DMODEL, DMODEL);
}